// Round 2
// baseline (694.899 us; speedup 1.0000x reference)
//
#include <hip/hip_runtime.h>
#include <math.h>

// Problem shape (fixed by the reference): B=16, S=4096, E=2048, WIN=64.
#define EDIM 2048
#define SLEN 4096
#define NROWS (16 * 4096)      // B*S = 65536
#define SBLOCKS 2048           // 8 blocks/CU * 256 CUs
#define ROWS_PER_WAVE 8        // 65536 rows / (2048*4 waves)

// Stage 1: grid-stride, one wave per row-pair per iteration.
// Each wave owns 8 contiguous rows; processes 2 at a time (16 float4 loads
// in flight). W staged in LDS once per block, amortized over 32 rows/block.
__global__ __launch_bounds__(256) void score_kernel(
    const float* __restrict__ x,
    const int*   __restrict__ mask,
    const float* __restrict__ W,
    const float* __restrict__ bias,
    float* __restrict__ s_out)
{
    __shared__ float4 wsh[EDIM / 4];  // 8 KB

    const int tid = threadIdx.x;
    const float4* W4 = (const float4*)W;
    wsh[tid]       = W4[tid];
    wsh[tid + 256] = W4[tid + 256];
    __syncthreads();

    const int lane  = tid & 63;
    const int gwave = blockIdx.x * 4 + (tid >> 6);   // 0..8191
    const int base  = gwave * ROWS_PER_WAVE;
    const float b0  = bias[0];

#pragma unroll
    for (int i = 0; i < ROWS_PER_WAVE / 2; ++i) {
        const int r0 = base + 2 * i;
        const int r1 = r0 + 1;
        const float4* x0 = (const float4*)(x + (size_t)r0 * EDIM);
        const float4* x1 = (const float4*)(x + (size_t)r1 * EDIM);

        float a0 = 0.0f, a1 = 0.0f;
#pragma unroll
        for (int k = 0; k < 8; ++k) {
            float4 v0 = x0[lane + 64 * k];
            float4 v1 = x1[lane + 64 * k];
            float4 wv = wsh[lane + 64 * k];
            a0 = fmaf(v0.x, wv.x, a0);
            a0 = fmaf(v0.y, wv.y, a0);
            a0 = fmaf(v0.z, wv.z, a0);
            a0 = fmaf(v0.w, wv.w, a0);
            a1 = fmaf(v1.x, wv.x, a1);
            a1 = fmaf(v1.y, wv.y, a1);
            a1 = fmaf(v1.z, wv.z, a1);
            a1 = fmaf(v1.w, wv.w, a1);
        }

#pragma unroll
        for (int off = 32; off > 0; off >>= 1) {
            a0 += __shfl_down(a0, off, 64);
            a1 += __shfl_down(a1, off, 64);
        }

        if (lane == 0) {
            s_out[r0] = mask[r0] ? (a0 + b0) : 0.0f;
            s_out[r1] = mask[r1] ? (a1 + b0) : 0.0f;
        }
    }
}

// Stage 2: one block per batch. Scores in LDS. Each thread owns a contiguous
// segment of window positions: computes the first window sum directly (with a
// per-thread rotated start so stride-16 segments don't all hit 2 LDS banks),
// then slides (sum += new - old). Block max-reduce, divide by win once.
__global__ __launch_bounds__(256) void window_max_kernel(
    const float* __restrict__ s,
    const int*   __restrict__ win_ptr,
    float* __restrict__ out)
{
    __shared__ float sh[SLEN];      // 16 KB
    __shared__ float red[256];

    const int b   = blockIdx.x;
    const int tid = threadIdx.x;
    const float* sb = s + (size_t)b * SLEN;

    for (int i = tid; i < SLEN; i += 256)
        sh[i] = sb[i];
    __syncthreads();

    const int win  = *win_ptr;
    const int npos = SLEN - win + 1;
    const int per  = (npos + 255) / 256;

    int p0 = tid * per;
    int p1 = p0 + per;
    if (p1 > npos) p1 = npos;

    float best = -INFINITY;
    if (p0 < npos) {
        // Direct sum of the first window, rotated start to spread LDS banks.
        const int start = tid & (win - 1) & 63;  // ok for pow2 win; see wrap below
        float sum = 0.0f;
        int off = (start < win) ? start : 0;
        for (int j = 0; j < win; ++j) {
            sum += sh[p0 + off];
            ++off;
            if (off >= win) off = 0;
        }
        best = sum;
        // Slide across the rest of the segment.
        for (int p = p0 + 1; p < p1; ++p) {
            sum += sh[p - 1 + win] - sh[p - 1];
            best = fmaxf(best, sum);
        }
    }

    red[tid] = best;
    __syncthreads();
    for (int k = 128; k > 0; k >>= 1) {
        if (tid < k) red[tid] = fmaxf(red[tid], red[tid + k]);
        __syncthreads();
    }
    if (tid == 0)
        out[b] = red[0] / (float)win;
}

extern "C" void kernel_launch(void* const* d_in, const int* in_sizes, int n_in,
                              void* d_out, int out_size, void* d_ws, size_t ws_size,
                              hipStream_t stream) {
    const float* x    = (const float*)d_in[0];  // [B,S,E] f32
    const int*   mask = (const int*)  d_in[1];  // [B,S]   bool->int
    const float* W    = (const float*)d_in[2];  // [E]     f32
    const float* bias = (const float*)d_in[3];  // [1]     f32
    const int*   win  = (const int*)  d_in[4];  // scalar  int

    float* out = (float*)d_out;                 // [B] f32
    float* s   = (float*)d_ws;                  // [B*S] f32 scratch (256 KB)

    const int B = out_size;                     // 16

    score_kernel<<<SBLOCKS, 256, 0, stream>>>(x, mask, W, bias, s);
    window_max_kernel<<<B, 256, 0, stream>>>(s, win, out);
}